// Round 1
// baseline (277.904 us; speedup 1.0000x reference)
//
#include <hip/hip_runtime.h>

// B=2, T=2048, C=1024, NH=16, NKV=4, D=64, window=1024 (read from d_in[9])
// Pipeline:
//  1) convert x -> bf16 (xb)
//  2) transpose Wq|Wk|Wv -> Wt[1536][1024] bf16 ; Wproj -> Wpt[1024][1024] bf16
//  3) gemm_bt: qkv_f32[4096][1536] = xb @ W
//  4) epilogue: gate+ve, RoPE, RMS-norm -> Qb[B][16][T][64], Kb[B][4][T][64], Vb[B][4][T][64] (bf16)
//  5) transpose Vb -> Vt[B][4][64][T]  (so PV B-fragments are contiguous-k in LDS)
//  6) flash attention (16x16x32 bf16 MFMA, online softmax) -> Y[4096][1024] bf16
//  7) gemm_bt: out = Y @ Wproj   (fp32 out)

typedef __bf16 bf16x8 __attribute__((ext_vector_type(8)));
typedef float  f32x4  __attribute__((ext_vector_type(4)));

// ---------------- prep kernels ----------------

__global__ void convert_f32_bf16(const float* __restrict__ in, __bf16* __restrict__ out, int n) {
  int i = (blockIdx.x * blockDim.x + threadIdx.x) * 8;
  if (i >= n) return;
  float4 a = *(const float4*)(in + i);
  float4 b = *(const float4*)(in + i + 4);
  bf16x8 o;
  o[0] = (__bf16)a.x; o[1] = (__bf16)a.y; o[2] = (__bf16)a.z; o[3] = (__bf16)a.w;
  o[4] = (__bf16)b.x; o[5] = (__bf16)b.y; o[6] = (__bf16)b.z; o[7] = (__bf16)b.w;
  *(bf16x8*)(out + i) = o;
}

// out[c][r] = (bf16) in[r][c];  in: [R][Cc] f32, out: [Cc][R] bf16. grid (Cc/32, R/32), 256 thr.
__global__ void transpose_f32_bf16(const float* __restrict__ in, __bf16* __restrict__ out,
                                   int R, int Cc) {
  __shared__ float tile[32][33];
  int c0 = blockIdx.x * 32, r0 = blockIdx.y * 32;
  int tx = threadIdx.x & 31, ty = threadIdx.x >> 5;  // ty: 0..7
  for (int i = ty; i < 32; i += 8) tile[i][tx] = in[(size_t)(r0 + i) * Cc + c0 + tx];
  __syncthreads();
  for (int i = ty; i < 32; i += 8) out[(size_t)(c0 + i) * R + r0 + tx] = (__bf16)tile[tx][i];
}

// batched bf16 transpose: in [Z][R][Cc] -> out [Z][Cc][R]. grid (Cc/32, R/32, Z)
__global__ void transpose_bf16(const __bf16* __restrict__ in, __bf16* __restrict__ out,
                               int R, int Cc) {
  __shared__ __bf16 tile[32][33];
  size_t boff = (size_t)blockIdx.z * R * Cc;
  int c0 = blockIdx.x * 32, r0 = blockIdx.y * 32;
  int tx = threadIdx.x & 31, ty = threadIdx.x >> 5;
  for (int i = ty; i < 32; i += 8) tile[i][tx] = in[boff + (size_t)(r0 + i) * Cc + c0 + tx];
  __syncthreads();
  for (int i = ty; i < 32; i += 8) out[boff + (size_t)(c0 + i) * R + r0 + tx] = tile[tx][i];
}

// ---------------- GEMM: C[M][N] = A[M][K] * B[K][N], B given transposed as Bt[N][K] -------------
// 128x128 tile, BK=32, 256 threads = 4 waves (2x2), each wave 64x64 via 4x4 of 16x16x32 MFMA.
__global__ __launch_bounds__(256) void gemm_bt(const __bf16* __restrict__ A,
                                               const __bf16* __restrict__ Bt,
                                               float* __restrict__ C,
                                               int M, int N, int K) {
  __shared__ __bf16 As[128 * 40];  // stride 40 bf16 (pad 8) -> 2-way-max LDS bank aliasing
  __shared__ __bf16 Bs[128 * 40];
  int tid = threadIdx.x;
  int m0 = blockIdx.y * 128, n0 = blockIdx.x * 128;
  int w = tid >> 6, lane = tid & 63, quad = lane >> 4, l16 = lane & 15;
  int wm = (w >> 1) * 64, wn = (w & 1) * 64;

  f32x4 zero = {0.f, 0.f, 0.f, 0.f};
  f32x4 acc[4][4];
  for (int i = 0; i < 4; ++i) for (int j = 0; j < 4; ++j) acc[i][j] = zero;

  int row = tid >> 2;        // 0..63
  int c8  = (tid & 3) * 8;   // 0,8,16,24
  const __bf16* Aptr = A  + (size_t)(m0 + row) * K + c8;
  const __bf16* Bptr = Bt + (size_t)(n0 + row) * K + c8;

  for (int k0 = 0; k0 < K; k0 += 32) {
    bf16x8 a0 = *(const bf16x8*)(Aptr);
    bf16x8 a1 = *(const bf16x8*)(Aptr + (size_t)64 * K);
    bf16x8 b0 = *(const bf16x8*)(Bptr);
    bf16x8 b1 = *(const bf16x8*)(Bptr + (size_t)64 * K);
    Aptr += 32; Bptr += 32;
    __syncthreads();
    *(bf16x8*)(&As[row * 40 + c8]) = a0;
    *(bf16x8*)(&As[(row + 64) * 40 + c8]) = a1;
    *(bf16x8*)(&Bs[row * 40 + c8]) = b0;
    *(bf16x8*)(&Bs[(row + 64) * 40 + c8]) = b1;
    __syncthreads();
    bf16x8 af[4], bfr[4];
    for (int i = 0; i < 4; ++i) {
      af[i]  = *(const bf16x8*)(&As[(wm + i * 16 + l16) * 40 + quad * 8]);
      bfr[i] = *(const bf16x8*)(&Bs[(wn + i * 16 + l16) * 40 + quad * 8]);
    }
    for (int i = 0; i < 4; ++i)
      for (int j = 0; j < 4; ++j)
        acc[i][j] = __builtin_amdgcn_mfma_f32_16x16x32_bf16(af[i], bfr[j], acc[i][j], 0, 0, 0);
  }
  // C/D layout: col = lane&15, row = quad*4 + r
  for (int i = 0; i < 4; ++i)
    for (int j = 0; j < 4; ++j)
      for (int r = 0; r < 4; ++r)
        C[(size_t)(m0 + wm + i * 16 + quad * 4 + r) * N + n0 + wn + j * 16 + l16] = acc[i][j][r];
}

// ---------------- epilogue: gate + RoPE + RMS-norm, fp32 in -> bf16 heads -------------
__global__ __launch_bounds__(256) void qkv_epilogue(
    const float* __restrict__ qkv, const float* __restrict__ x,
    const float* __restrict__ ve, const float* __restrict__ cosp,
    const float* __restrict__ sinp, const float* __restrict__ Wg,
    __bf16* __restrict__ Qb, __bf16* __restrict__ Kb, __bf16* __restrict__ Vb) {
  const int T = 2048;
  int bt = blockIdx.x;
  int b = bt >> 11, t = bt & 2047;
  int w = threadIdx.x >> 6, d = threadIdx.x & 63;
  int i = d & 31;
  float c = cosp[t * 32 + i], s = sinp[t * 32 + i];
  const float* row = qkv + (size_t)bt * 1536;

  // 16 q heads: wave w handles h = w, w+4, w+8, w+12
  for (int h = w; h < 16; h += 4) {
    float v = row[h * 64 + d];
    float other = __shfl_xor(v, 32, 64);
    float rv = v * c + ((d < 32) ? other * s : -other * s);
    float ss = rv * rv;
    for (int off = 1; off < 64; off <<= 1) ss += __shfl_xor(ss, off, 64);
    float out = rv * rsqrtf(ss * (1.f / 64.f) + 1e-6f) * 1.2f;
    Qb[(((size_t)b * 16 + h) * T + t) * 64 + d] = (__bf16)out;
  }
  // 4 k heads
  {
    int kvh = w;
    float v = row[1024 + kvh * 64 + d];
    float other = __shfl_xor(v, 32, 64);
    float rv = v * c + ((d < 32) ? other * s : -other * s);
    float ss = rv * rv;
    for (int off = 1; off < 64; off <<= 1) ss += __shfl_xor(ss, off, 64);
    float out = rv * rsqrtf(ss * (1.f / 64.f) + 1e-6f) * 1.2f;
    Kb[(((size_t)b * 4 + kvh) * T + t) * 64 + d] = (__bf16)out;
  }
  // 4 v heads: v + 3*sigmoid(x[:12]@Wg) * ve
  {
    int kvh = w;
    float v = row[1280 + kvh * 64 + d];
    float dot = 0.f;
    for (int j = 0; j < 12; ++j) dot += x[(size_t)bt * 1024 + j] * Wg[j * 4 + kvh];
    float g = 3.f / (1.f + expf(-dot));
    float out = v + g * ve[(size_t)bt * 256 + kvh * 64 + d];
    Vb[(((size_t)b * 4 + kvh) * T + t) * 64 + d] = (__bf16)out;
  }
}

// ---------------- flash attention (sliding window causal, GQA) ----------------
// grid (T/64, NH, B), 256 threads = 4 waves; wave w handles 16 queries qb+16w..+16.
// Q: [B][NH][T][64] bf16, K: [B][NKV][T][64] bf16, Vt: [B][NKV][64][T] bf16,
// Y: [B*T][NH*64] bf16.
__global__ __launch_bounds__(256) void attn_kernel(
    const __bf16* __restrict__ Q, const __bf16* __restrict__ K,
    const __bf16* __restrict__ Vt, __bf16* __restrict__ Y,
    const int* __restrict__ winp) {
  const int T = 2048, D = 64, NH = 16, NKV = 4;
  int b = blockIdx.z, h = blockIdx.y, qb = blockIdx.x * 64;
  int kvh = h >> 2;
  int tid = threadIdx.x, w = tid >> 6, lane = tid & 63, quad = lane >> 4, l16 = lane & 15;
  int window = *winp;
  int qw = qb + w * 16;
  const float scale = 0.125f;  // 1/sqrt(64)

  __shared__ __bf16 Ks[32 * 88];      // [key_local][d], stride 88 (2-way aliasing max)
  __shared__ __bf16 Vs[64 * 40];      // [d][key_local], stride 40
  __shared__ __bf16 Ps[4 * 16 * 40];  // per-wave P transpose scratch [q][key_local], stride 40

  const __bf16* Qbase = Q + ((size_t)(b * NH + h)) * T * D;
  bf16x8 qf0 = *(const bf16x8*)(Qbase + (size_t)(qw + l16) * D + quad * 8);
  bf16x8 qf1 = *(const bf16x8*)(Qbase + (size_t)(qw + l16) * D + quad * 8 + 32);

  const __bf16* Kbase = K  + ((size_t)(b * NKV + kvh)) * T * D;
  const __bf16* Vbase = Vt + ((size_t)(b * NKV + kvh)) * D * T;

  float mi[4] = {-1e30f, -1e30f, -1e30f, -1e30f};
  float li[4] = {0.f, 0.f, 0.f, 0.f};
  f32x4 zero = {0.f, 0.f, 0.f, 0.f};
  f32x4 o0 = zero, o1 = zero, o2 = zero, o3 = zero;

  int kstart = qb - window; if (kstart < 0) kstart = 0; kstart &= ~31;
  int kend = qb + 64;

  for (int kt = kstart; kt < kend; kt += 32) {
    __syncthreads();
    {  // stage K tile (32x64) and V tile (64 d x 32 keys)
      int krow = tid >> 3, kc8 = (tid & 7) * 8;
      bf16x8 kv = *(const bf16x8*)(Kbase + (size_t)(kt + krow) * D + kc8);
      *(bf16x8*)(&Ks[krow * 88 + kc8]) = kv;
      int dr = tid >> 2, k8 = (tid & 3) * 8;
      bf16x8 vv = *(const bf16x8*)(Vbase + (size_t)dr * T + kt + k8);
      *(bf16x8*)(&Vs[dr * 40 + k8]) = vv;
    }
    __syncthreads();
    if (kt > qw + 15 || kt + 31 < qw - window) continue;  // tile fully masked for this wave

    // S = Q K^T : 16 q x 32 keys
    f32x4 s0 = zero, s1 = zero;
    {
      bf16x8 k00 = *(const bf16x8*)(&Ks[l16 * 88 + quad * 8]);
      bf16x8 k01 = *(const bf16x8*)(&Ks[l16 * 88 + quad * 8 + 32]);
      bf16x8 k10 = *(const bf16x8*)(&Ks[(16 + l16) * 88 + quad * 8]);
      bf16x8 k11 = *(const bf16x8*)(&Ks[(16 + l16) * 88 + quad * 8 + 32]);
      s0 = __builtin_amdgcn_mfma_f32_16x16x32_bf16(qf0, k00, s0, 0, 0, 0);
      s0 = __builtin_amdgcn_mfma_f32_16x16x32_bf16(qf1, k01, s0, 0, 0, 0);
      s1 = __builtin_amdgcn_mfma_f32_16x16x32_bf16(qf0, k10, s1, 0, 0, 0);
      s1 = __builtin_amdgcn_mfma_f32_16x16x32_bf16(qf1, k11, s1, 0, 0, 0);
    }
    // online softmax; S row = q = qw + quad*4 + r, col = key = kt + kg*16 + l16
    for (int r = 0; r < 4; ++r) {
      int q = qw + quad * 4 + r;
      int k0i = kt + l16, k1i = kt + 16 + l16;
      float v0 = s0[r] * scale + ((k0i <= q && q - k0i <= window) ? 0.f : -1e9f);
      float v1 = s1[r] * scale + ((k1i <= q && q - k1i <= window) ? 0.f : -1e9f);
      float mt = fmaxf(v0, v1);
      for (int off = 1; off < 16; off <<= 1) mt = fmaxf(mt, __shfl_xor(mt, off, 64));
      float mnew = fmaxf(mi[r], mt);
      float alpha = expf(mi[r] - mnew);
      float pa = expf(v0 - mnew), pb = expf(v1 - mnew);
      float rs = pa + pb;
      for (int off = 1; off < 16; off <<= 1) rs += __shfl_xor(rs, off, 64);
      li[r] = li[r] * alpha + rs;
      mi[r] = mnew;
      o0[r] *= alpha; o1[r] *= alpha; o2[r] *= alpha; o3[r] *= alpha;
      Ps[w * 640 + (quad * 4 + r) * 40 + l16] = (__bf16)pa;
      Ps[w * 640 + (quad * 4 + r) * 40 + 16 + l16] = (__bf16)pb;
    }
    // P (A-layout) and V (B-layout) fragments; K-dim = 32 keys
    bf16x8 pf  = *(const bf16x8*)(&Ps[w * 640 + l16 * 40 + quad * 8]);
    bf16x8 vf0 = *(const bf16x8*)(&Vs[(l16) * 40 + quad * 8]);
    bf16x8 vf1 = *(const bf16x8*)(&Vs[(16 + l16) * 40 + quad * 8]);
    bf16x8 vf2 = *(const bf16x8*)(&Vs[(32 + l16) * 40 + quad * 8]);
    bf16x8 vf3 = *(const bf16x8*)(&Vs[(48 + l16) * 40 + quad * 8]);
    o0 = __builtin_amdgcn_mfma_f32_16x16x32_bf16(pf, vf0, o0, 0, 0, 0);
    o1 = __builtin_amdgcn_mfma_f32_16x16x32_bf16(pf, vf1, o1, 0, 0, 0);
    o2 = __builtin_amdgcn_mfma_f32_16x16x32_bf16(pf, vf2, o2, 0, 0, 0);
    o3 = __builtin_amdgcn_mfma_f32_16x16x32_bf16(pf, vf3, o3, 0, 0, 0);
  }

  for (int r = 0; r < 4; ++r) {
    float inv = 1.f / li[r];
    size_t base = ((size_t)(b * T + qw + quad * 4 + r)) * 1024 + h * 64 + l16;
    Y[base +  0] = (__bf16)(o0[r] * inv);
    Y[base + 16] = (__bf16)(o1[r] * inv);
    Y[base + 32] = (__bf16)(o2[r] * inv);
    Y[base + 48] = (__bf16)(o3[r] * inv);
  }
}

// ---------------- launch ----------------
extern "C" void kernel_launch(void* const* d_in, const int* in_sizes, int n_in,
                              void* d_out, int out_size, void* d_ws, size_t ws_size,
                              hipStream_t stream) {
  const float* x     = (const float*)d_in[0];
  const float* ve    = (const float*)d_in[1];
  const float* cosp  = (const float*)d_in[2];
  const float* sinp  = (const float*)d_in[3];
  const float* Wq    = (const float*)d_in[4];
  const float* Wk    = (const float*)d_in[5];
  const float* Wv    = (const float*)d_in[6];
  const float* Wproj = (const float*)d_in[7];
  const float* Wg    = (const float*)d_in[8];
  const int*   win   = (const int*)d_in[9];
  float* out = (float*)d_out;

  char* ws = (char*)d_ws;
  __bf16* xb  = (__bf16*)(ws);                 //  8,388,608  x as bf16 [4096][1024]
  __bf16* Wt  = (__bf16*)(ws + 8388608);       //  3,145,728  [1536][1024] (q|k|v cols, transposed)
  __bf16* Wpt = (__bf16*)(ws + 11534336);      //  2,097,152  [1024][1024]
  float*  qkv = (float*)(ws + 13631488);       // 25,165,824  [4096][1536] f32
  __bf16* Qb  = (__bf16*)(ws + 38797312);      //  8,388,608  [2][16][2048][64]
  __bf16* Kb  = (__bf16*)(ws + 47185920);      //  2,097,152  [2][4][2048][64]
  __bf16* Vb  = (__bf16*)(ws + 49283072);      //  2,097,152  [2][4][2048][64]
  __bf16* Vt  = (__bf16*)(ws + 51380224);      //  2,097,152  [2][4][64][2048]
  __bf16* Y   = (__bf16*)(ws + 53477376);      //  8,388,608  [4096][1024]  (ends 61,865,984)

  // 1) x -> bf16
  convert_f32_bf16<<<2048, 256, 0, stream>>>(x, xb, 4096 * 1024);
  // 2) weight transposes (f32 -> bf16)
  transpose_f32_bf16<<<dim3(32, 32), 256, 0, stream>>>(Wq, Wt, 1024, 1024);
  transpose_f32_bf16<<<dim3(8, 32), 256, 0, stream>>>(Wk, Wt + 1024 * 1024, 1024, 256);
  transpose_f32_bf16<<<dim3(8, 32), 256, 0, stream>>>(Wv, Wt + 1280 * 1024, 1024, 256);
  transpose_f32_bf16<<<dim3(32, 32), 256, 0, stream>>>(Wproj, Wpt, 1024, 1024);
  // 3) qkv = x @ [Wq|Wk|Wv]
  gemm_bt<<<dim3(12, 32), 256, 0, stream>>>(xb, Wt, qkv, 4096, 1536, 1024);
  // 4) gate + rope + rms-norm
  qkv_epilogue<<<4096, 256, 0, stream>>>(qkv, x, ve, cosp, sinp, Wg, Qb, Kb, Vb);
  // 5) V -> [b][kvh][d][t]
  transpose_bf16<<<dim3(2, 64, 8), 256, 0, stream>>>(Vb, Vt, 2048, 64);
  // 6) attention
  attn_kernel<<<dim3(32, 16, 2), 256, 0, stream>>>(Qb, Kb, Vt, Y, win);
  // 7) out = Y @ Wproj
  gemm_bt<<<dim3(8, 32), 256, 0, stream>>>(Y, Wpt, out, 4096, 1024, 1024);
}

// Round 2
// 226.397 us; speedup vs baseline: 1.2275x; 1.2275x over previous
//
#include <hip/hip_runtime.h>

// B=2, T=2048, C=1024, NH=16, NKV=4, D=64, window read from d_in[9]
// Pipeline:
//  1) convert x -> bf16 (xb)
//  2) transpose Wq|Wk|Wv -> Wt[1536][1024] bf16 ; Wproj -> Wpt[1024][1024] bf16
//  3) gemm_bt (global_load_lds staging): qkv_f32[4096][1536] = xb @ W
//  4) epilogue: gate+ve, RoPE, RMS-norm -> Qb[B][16][T][64], Kb[B][4][T][64], Vb[B][4][T][64]
//  5) transpose Vb -> Vt[B][4][64][T]
//  6) flash attention, FIXED-MAX softmax (scores provably <= 11.6 < 12), 64-key tiles
//  7) gemm_bt: out = Y @ Wproj (fp32 out)

typedef __bf16 bf16x8 __attribute__((ext_vector_type(8)));
typedef float  f32x4  __attribute__((ext_vector_type(4)));

__device__ __forceinline__ void g2l16(const __bf16* gp, __bf16* lp) {
  // async global->LDS, 16 bytes per lane; LDS dest = wave-uniform base + lane*16
  __builtin_amdgcn_global_load_lds(
      (const __attribute__((address_space(1))) unsigned int*)(const void*)gp,
      (__attribute__((address_space(3))) unsigned int*)(void*)lp, 16, 0, 0);
}

// ---------------- prep kernels ----------------

__global__ void convert_f32_bf16(const float* __restrict__ in, __bf16* __restrict__ out, int n) {
  int i = (blockIdx.x * blockDim.x + threadIdx.x) * 8;
  if (i >= n) return;
  float4 a = *(const float4*)(in + i);
  float4 b = *(const float4*)(in + i + 4);
  bf16x8 o;
  o[0] = (__bf16)a.x; o[1] = (__bf16)a.y; o[2] = (__bf16)a.z; o[3] = (__bf16)a.w;
  o[4] = (__bf16)b.x; o[5] = (__bf16)b.y; o[6] = (__bf16)b.z; o[7] = (__bf16)b.w;
  *(bf16x8*)(out + i) = o;
}

__global__ void transpose_f32_bf16(const float* __restrict__ in, __bf16* __restrict__ out,
                                   int R, int Cc) {
  __shared__ float tile[32][33];
  int c0 = blockIdx.x * 32, r0 = blockIdx.y * 32;
  int tx = threadIdx.x & 31, ty = threadIdx.x >> 5;
  for (int i = ty; i < 32; i += 8) tile[i][tx] = in[(size_t)(r0 + i) * Cc + c0 + tx];
  __syncthreads();
  for (int i = ty; i < 32; i += 8) out[(size_t)(c0 + i) * R + r0 + tx] = (__bf16)tile[tx][i];
}

__global__ void transpose_bf16(const __bf16* __restrict__ in, __bf16* __restrict__ out,
                               int R, int Cc) {
  __shared__ __bf16 tile[32][33];
  size_t boff = (size_t)blockIdx.z * R * Cc;
  int c0 = blockIdx.x * 32, r0 = blockIdx.y * 32;
  int tx = threadIdx.x & 31, ty = threadIdx.x >> 5;
  for (int i = ty; i < 32; i += 8) tile[i][tx] = in[boff + (size_t)(r0 + i) * Cc + c0 + tx];
  __syncthreads();
  for (int i = ty; i < 32; i += 8) out[boff + (size_t)(c0 + i) * R + r0 + tx] = tile[tx][i];
}

// ---------------- GEMM: C[M][N] = A[M][K] * Bt[N][K]^T, m97-style global_load_lds staging ----
__global__ __launch_bounds__(256) void gemm_bt(const __bf16* __restrict__ A,
                                               const __bf16* __restrict__ Bt,
                                               float* __restrict__ C,
                                               int M, int N, int K) {
  __shared__ __bf16 As[128 * 32];  // unpadded: required by global_load_lds lane-contiguous dest
  __shared__ __bf16 Bs[128 * 32];
  int tid = threadIdx.x;
  int m0 = blockIdx.y * 128, n0 = blockIdx.x * 128;
  int w = tid >> 6, lane = tid & 63, quad = lane >> 4, l16 = lane & 15;
  int wm = (w >> 1) * 64, wn = (w & 1) * 64;

  f32x4 zero = {0.f, 0.f, 0.f, 0.f};
  f32x4 acc[4][4];
  for (int i = 0; i < 4; ++i) for (int j = 0; j < 4; ++j) acc[i][j] = zero;

  // each wave stages 2 chunks (16 rows x 32 cols = 1KB) of A and of B
  int ch0 = w * 2, ch1 = w * 2 + 1;
  int rsub = lane >> 2, cc = (lane & 3) * 8;
  const __bf16* gA0 = A + (size_t)(m0 + ch0 * 16 + rsub) * K + cc;
  const __bf16* gA1 = A + (size_t)(m0 + ch1 * 16 + rsub) * K + cc;
  const __bf16* gB0 = Bt + (size_t)(n0 + ch0 * 16 + rsub) * K + cc;
  const __bf16* gB1 = Bt + (size_t)(n0 + ch1 * 16 + rsub) * K + cc;
  __bf16* lA0 = &As[ch0 * 512];
  __bf16* lA1 = &As[ch1 * 512];
  __bf16* lB0 = &Bs[ch0 * 512];
  __bf16* lB1 = &Bs[ch1 * 512];

  for (int k0 = 0; k0 < K; k0 += 32) {
    __syncthreads();  // previous iter's LDS reads complete before overwrite
    g2l16(gA0 + k0, lA0);
    g2l16(gA1 + k0, lA1);
    g2l16(gB0 + k0, lB0);
    g2l16(gB1 + k0, lB1);
    __syncthreads();  // drains vmcnt -> staged data visible
    bf16x8 af[4], bfr[4];
    for (int i = 0; i < 4; ++i) {
      af[i]  = *(const bf16x8*)(&As[(wm + i * 16 + l16) * 32 + quad * 8]);
      bfr[i] = *(const bf16x8*)(&Bs[(wn + i * 16 + l16) * 32 + quad * 8]);
    }
    for (int i = 0; i < 4; ++i)
      for (int j = 0; j < 4; ++j)
        acc[i][j] = __builtin_amdgcn_mfma_f32_16x16x32_bf16(af[i], bfr[j], acc[i][j], 0, 0, 0);
  }
  for (int i = 0; i < 4; ++i)
    for (int j = 0; j < 4; ++j)
      for (int r = 0; r < 4; ++r)
        C[(size_t)(m0 + wm + i * 16 + quad * 4 + r) * N + n0 + wn + j * 16 + l16] = acc[i][j][r];
}

// ---------------- epilogue: gate + RoPE + RMS-norm ----------------
__global__ __launch_bounds__(256) void qkv_epilogue(
    const float* __restrict__ qkv, const float* __restrict__ x,
    const float* __restrict__ ve, const float* __restrict__ cosp,
    const float* __restrict__ sinp, const float* __restrict__ Wg,
    __bf16* __restrict__ Qb, __bf16* __restrict__ Kb, __bf16* __restrict__ Vb) {
  const int T = 2048;
  int bt = blockIdx.x;
  int b = bt >> 11, t = bt & 2047;
  int w = threadIdx.x >> 6, d = threadIdx.x & 63;
  int i = d & 31;
  float c = cosp[t * 32 + i], s = sinp[t * 32 + i];
  const float* row = qkv + (size_t)bt * 1536;

  for (int h = w; h < 16; h += 4) {
    float v = row[h * 64 + d];
    float other = __shfl_xor(v, 32, 64);
    float rv = v * c + ((d < 32) ? other * s : -other * s);
    float ss = rv * rv;
    for (int off = 1; off < 64; off <<= 1) ss += __shfl_xor(ss, off, 64);
    float out = rv * rsqrtf(ss * (1.f / 64.f) + 1e-6f) * 1.2f;
    Qb[(((size_t)b * 16 + h) * T + t) * 64 + d] = (__bf16)out;
  }
  {
    int kvh = w;
    float v = row[1024 + kvh * 64 + d];
    float other = __shfl_xor(v, 32, 64);
    float rv = v * c + ((d < 32) ? other * s : -other * s);
    float ss = rv * rv;
    for (int off = 1; off < 64; off <<= 1) ss += __shfl_xor(ss, off, 64);
    float out = rv * rsqrtf(ss * (1.f / 64.f) + 1e-6f) * 1.2f;
    Kb[(((size_t)b * 4 + kvh) * T + t) * 64 + d] = (__bf16)out;
  }
  {
    int kvh = w;
    float v = row[1280 + kvh * 64 + d];
    float dot = 0.f;
    for (int j = 0; j < 12; ++j) dot += x[(size_t)bt * 1024 + j] * Wg[j * 4 + kvh];
    float g = 3.f / (1.f + expf(-dot));
    float out = v + g * ve[(size_t)bt * 256 + kvh * 64 + d];
    Vb[(((size_t)b * 4 + kvh) * T + t) * 64 + d] = (__bf16)out;
  }
}

// ---------------- flash attention, fixed-max softmax, 64-key tiles ----------------
// Scores bounded: ||q||,||k|| <= 9.64 (bf16-rounded) -> |s*scale| <= 11.62 < 12.
// p = exp2(s*scale*log2e - 12*log2e); masked -> 0. No in-loop reductions, no O rescale.
__global__ __launch_bounds__(256) void attn_kernel(
    const __bf16* __restrict__ Q, const __bf16* __restrict__ K,
    const __bf16* __restrict__ Vt, __bf16* __restrict__ Y,
    const int* __restrict__ winp) {
  const int T = 2048, D = 64, NH = 16, NKV = 4;
  int b = blockIdx.z, h = blockIdx.y, qb = blockIdx.x * 64;
  int kvh = h >> 2;
  int tid = threadIdx.x, w = tid >> 6, lane = tid & 63, quad = lane >> 4, l16 = lane & 15;
  int window = *winp;
  int qw = qb + w * 16;

  __shared__ __bf16 Ks[64 * 72];      // [key][d]
  __shared__ __bf16 Vs[64 * 72];      // [d][key]
  __shared__ __bf16 Ps[4 * 16 * 72];  // per-wave [q][key]

  const __bf16* Qbase = Q + ((size_t)(b * NH + h)) * T * D;
  bf16x8 qf0 = *(const bf16x8*)(Qbase + (size_t)(qw + l16) * D + quad * 8);
  bf16x8 qf1 = *(const bf16x8*)(Qbase + (size_t)(qw + l16) * D + quad * 8 + 32);

  const __bf16* Kbase = K  + ((size_t)(b * NKV + kvh)) * T * D;
  const __bf16* Vbase = Vt + ((size_t)(b * NKV + kvh)) * D * T;

  float lsum[4] = {0.f, 0.f, 0.f, 0.f};
  f32x4 zero = {0.f, 0.f, 0.f, 0.f};
  f32x4 o[4] = {zero, zero, zero, zero};

  int kstart = qb - window; if (kstart < 0) kstart = 0; kstart &= ~63;
  int kend = qb + 64;
  const float c1 = 0.125f * 1.44269504f;   // scale * log2(e)
  const float c2 = 12.0f * 1.44269504f;    // fixed max * log2(e)

  for (int kt = kstart; kt < kend; kt += 64) {
    bf16x8 kr[2], vr[2];
    for (int j = 0; j < 2; ++j) {
      int ch = tid + j * 256;
      int r = ch >> 3, c8 = (ch & 7) * 8;
      kr[j] = *(const bf16x8*)(Kbase + (size_t)(kt + r) * D + c8);
      vr[j] = *(const bf16x8*)(Vbase + (size_t)r * T + kt + c8);
    }
    __syncthreads();
    for (int j = 0; j < 2; ++j) {
      int ch = tid + j * 256;
      int r = ch >> 3, c8 = (ch & 7) * 8;
      *(bf16x8*)(&Ks[r * 72 + c8]) = kr[j];
      *(bf16x8*)(&Vs[r * 72 + c8]) = vr[j];
    }
    __syncthreads();
    if (kt > qw + 15 || kt + 63 < qw - window) continue;  // wave fully masked this tile

    f32x4 s[4];
    for (int kg = 0; kg < 4; ++kg) {
      bf16x8 k0 = *(const bf16x8*)(&Ks[(kg * 16 + l16) * 72 + quad * 8]);
      bf16x8 k1 = *(const bf16x8*)(&Ks[(kg * 16 + l16) * 72 + quad * 8 + 32]);
      s[kg] = __builtin_amdgcn_mfma_f32_16x16x32_bf16(qf0, k0, zero, 0, 0, 0);
      s[kg] = __builtin_amdgcn_mfma_f32_16x16x32_bf16(qf1, k1, s[kg], 0, 0, 0);
    }
    for (int r = 0; r < 4; ++r) {
      int q = qw + quad * 4 + r;
      for (int kg = 0; kg < 4; ++kg) {
        int ki = kt + kg * 16 + l16;
        bool ok = (ki <= q) && (q - ki <= window);
        float p = ok ? exp2f(s[kg][r] * c1 - c2) : 0.f;
        lsum[r] += p;
        Ps[w * 1152 + (quad * 4 + r) * 72 + kg * 16 + l16] = (__bf16)p;
      }
    }
    for (int koff = 0; koff < 64; koff += 32) {
      bf16x8 pf = *(const bf16x8*)(&Ps[w * 1152 + l16 * 72 + koff + quad * 8]);
      for (int j = 0; j < 4; ++j) {
        bf16x8 vf = *(const bf16x8*)(&Vs[(j * 16 + l16) * 72 + koff + quad * 8]);
        o[j] = __builtin_amdgcn_mfma_f32_16x16x32_bf16(pf, vf, o[j], 0, 0, 0);
      }
    }
  }

  for (int r = 0; r < 4; ++r) {
    float l = lsum[r];
    for (int off = 1; off < 16; off <<= 1) l += __shfl_xor(l, off, 64);
    float inv = 1.f / l;
    size_t base = ((size_t)(b * T + qw + quad * 4 + r)) * 1024 + h * 64 + l16;
    Y[base +  0] = (__bf16)(o[0][r] * inv);
    Y[base + 16] = (__bf16)(o[1][r] * inv);
    Y[base + 32] = (__bf16)(o[2][r] * inv);
    Y[base + 48] = (__bf16)(o[3][r] * inv);
  }
}

// ---------------- launch ----------------
extern "C" void kernel_launch(void* const* d_in, const int* in_sizes, int n_in,
                              void* d_out, int out_size, void* d_ws, size_t ws_size,
                              hipStream_t stream) {
  const float* x     = (const float*)d_in[0];
  const float* ve    = (const float*)d_in[1];
  const float* cosp  = (const float*)d_in[2];
  const float* sinp  = (const float*)d_in[3];
  const float* Wq    = (const float*)d_in[4];
  const float* Wk    = (const float*)d_in[5];
  const float* Wv    = (const float*)d_in[6];
  const float* Wproj = (const float*)d_in[7];
  const float* Wg    = (const float*)d_in[8];
  const int*   win   = (const int*)d_in[9];
  float* out = (float*)d_out;

  char* ws = (char*)d_ws;
  __bf16* xb  = (__bf16*)(ws);                 //  8,388,608
  __bf16* Wt  = (__bf16*)(ws + 8388608);       //  3,145,728
  __bf16* Wpt = (__bf16*)(ws + 11534336);      //  2,097,152
  float*  qkv = (float*)(ws + 13631488);       // 25,165,824
  __bf16* Qb  = (__bf16*)(ws + 38797312);      //  8,388,608
  __bf16* Kb  = (__bf16*)(ws + 47185920);      //  2,097,152
  __bf16* Vb  = (__bf16*)(ws + 49283072);      //  2,097,152
  __bf16* Vt  = (__bf16*)(ws + 51380224);      //  2,097,152
  __bf16* Y   = (__bf16*)(ws + 53477376);      //  8,388,608

  convert_f32_bf16<<<2048, 256, 0, stream>>>(x, xb, 4096 * 1024);
  transpose_f32_bf16<<<dim3(32, 32), 256, 0, stream>>>(Wq, Wt, 1024, 1024);
  transpose_f32_bf16<<<dim3(8, 32), 256, 0, stream>>>(Wk, Wt + 1024 * 1024, 1024, 256);
  transpose_f32_bf16<<<dim3(8, 32), 256, 0, stream>>>(Wv, Wt + 1280 * 1024, 1024, 256);
  transpose_f32_bf16<<<dim3(32, 32), 256, 0, stream>>>(Wproj, Wpt, 1024, 1024);
  gemm_bt<<<dim3(12, 32), 256, 0, stream>>>(xb, Wt, qkv, 4096, 1536, 1024);
  qkv_epilogue<<<4096, 256, 0, stream>>>(qkv, x, ve, cosp, sinp, Wg, Qb, Kb, Vb);
  transpose_bf16<<<dim3(2, 64, 8), 256, 0, stream>>>(Vb, Vt, 2048, 64);
  attn_kernel<<<dim3(32, 16, 2), 256, 0, stream>>>(Qb, Kb, Vt, Y, win);
  gemm_bt<<<dim3(8, 32), 256, 0, stream>>>(Y, Wpt, out, 4096, 1024, 1024);
}

// Round 3
// 198.543 us; speedup vs baseline: 1.3997x; 1.1403x over previous
//
#include <hip/hip_runtime.h>

// B=2, T=2048, C=1024, NH=16, NKV=4, D=64, window read from d_in[9]
// 5-kernel pipeline:
//  1) convert_gate: x -> bf16, plus gate[4096][4] = 3*sigmoid(x[:,:12] @ Wg)
//  2) transpose_weights: Wq|Wk|Wv -> Wt[1536][1024] bf16, Wproj -> Wpt[1024][1024] bf16
//  3) gemm_qkv: xb @ W with FUSED RoPE+RMS (Q,K) / gate+ve (V) epilogue
//       -> Qb[B][16][T][64], Kb[B][4][T][64], Vt[B][4][64][T]  (bf16, V pre-transposed)
//  4) attn: flash attention, fixed-max softmax, 64-key tiles, 8 waves, pipelined prefetch
//  5) gemm_bt: out = Y @ Wproj (fp32)

typedef __bf16 bf16x8 __attribute__((ext_vector_type(8)));
typedef __bf16 bf16x4 __attribute__((ext_vector_type(4)));
typedef float  f32x4  __attribute__((ext_vector_type(4)));

__device__ __forceinline__ void g2l16(const __bf16* gp, __bf16* lp) {
  __builtin_amdgcn_global_load_lds(
      (const __attribute__((address_space(1))) unsigned int*)(const void*)gp,
      (__attribute__((address_space(3))) unsigned int*)(void*)lp, 16, 0, 0);
}

// ---------------- 1) convert + gate ----------------
__global__ void convert_gate(const float* __restrict__ in, __bf16* __restrict__ out,
                             float* __restrict__ gate, const float* __restrict__ Wg) {
  int i = (blockIdx.x * blockDim.x + threadIdx.x) * 8;
  float4 a = *(const float4*)(in + i);
  float4 b = *(const float4*)(in + i + 4);
  bf16x8 o;
  o[0] = (__bf16)a.x; o[1] = (__bf16)a.y; o[2] = (__bf16)a.z; o[3] = (__bf16)a.w;
  o[4] = (__bf16)b.x; o[5] = (__bf16)b.y; o[6] = (__bf16)b.z; o[7] = (__bf16)b.w;
  *(bf16x8*)(out + i) = o;
  if (threadIdx.x < 8) {  // block covers rows 2*blockIdx, 2*blockIdx+1 of x[4096][1024]
    int row = blockIdx.x * 2 + (threadIdx.x >> 2);
    int kvh = threadIdx.x & 3;
    float dot = 0.f;
    for (int j = 0; j < 12; ++j) dot += in[(size_t)row * 1024 + j] * Wg[j * 4 + kvh];
    gate[row * 4 + kvh] = 3.f / (1.f + expf(-dot));
  }
}

// ---------------- 2) merged weight transposes ----------------
__global__ void transpose_weights(const float* __restrict__ Wq, const float* __restrict__ Wk,
                                  const float* __restrict__ Wv, const float* __restrict__ Wp,
                                  __bf16* __restrict__ Wt, __bf16* __restrict__ Wpt) {
  __shared__ float tile[32][33];
  int z = blockIdx.z;
  const float* in; __bf16* out; int Cc;
  if (z == 0)      { in = Wq; out = Wt;                 Cc = 1024; }
  else if (z == 1) { in = Wk; out = Wt + 1024 * 1024;   Cc = 256; }
  else if (z == 2) { in = Wv; out = Wt + 1280 * 1024;   Cc = 256; }
  else             { in = Wp; out = Wpt;                Cc = 1024; }
  const int R = 1024;
  int c0 = blockIdx.x * 32, r0 = blockIdx.y * 32;
  if (c0 >= Cc) return;
  int tx = threadIdx.x & 31, ty = threadIdx.x >> 5;
  for (int i = ty; i < 32; i += 8) tile[i][tx] = in[(size_t)(r0 + i) * Cc + c0 + tx];
  __syncthreads();
  for (int i = ty; i < 32; i += 8) out[(size_t)(c0 + i) * R + r0 + tx] = (__bf16)tile[tx][i];
}

// ---------------- 3) QKV GEMM with fused head epilogue ----------------
// A=xb[4096][1024], Bt=Wt[1536][1024]. grid (12,32). Wave strip = 64 cols = one head.
__global__ __launch_bounds__(256) void gemm_qkv(const __bf16* __restrict__ A,
                                                const __bf16* __restrict__ Bt,
                                                const float* __restrict__ cosp,
                                                const float* __restrict__ sinp,
                                                const float* __restrict__ gate,
                                                const float* __restrict__ ve,
                                                __bf16* __restrict__ Qb,
                                                __bf16* __restrict__ Kb,
                                                __bf16* __restrict__ Vt) {
  const int K = 1024;
  __shared__ __bf16 As[128 * 32];
  __shared__ __bf16 Bs[128 * 32];
  int tid = threadIdx.x;
  int m0 = blockIdx.y * 128, n0 = blockIdx.x * 128;
  int w = tid >> 6, lane = tid & 63, quad = lane >> 4, l16 = lane & 15;
  int wm = (w >> 1) * 64, wn = (w & 1) * 64;

  f32x4 zero = {0.f, 0.f, 0.f, 0.f};
  f32x4 acc[4][4];
  for (int i = 0; i < 4; ++i) for (int j = 0; j < 4; ++j) acc[i][j] = zero;

  int ch0 = w * 2, ch1 = w * 2 + 1;
  int rsub = lane >> 2, cc = (lane & 3) * 8;
  const __bf16* gA0 = A + (size_t)(m0 + ch0 * 16 + rsub) * K + cc;
  const __bf16* gA1 = A + (size_t)(m0 + ch1 * 16 + rsub) * K + cc;
  const __bf16* gB0 = Bt + (size_t)(n0 + ch0 * 16 + rsub) * K + cc;
  const __bf16* gB1 = Bt + (size_t)(n0 + ch1 * 16 + rsub) * K + cc;
  __bf16* lA0 = &As[ch0 * 512]; __bf16* lA1 = &As[ch1 * 512];
  __bf16* lB0 = &Bs[ch0 * 512]; __bf16* lB1 = &Bs[ch1 * 512];

  for (int k0 = 0; k0 < K; k0 += 32) {
    __syncthreads();
    g2l16(gA0 + k0, lA0);
    g2l16(gA1 + k0, lA1);
    g2l16(gB0 + k0, lB0);
    g2l16(gB1 + k0, lB1);
    __syncthreads();
    bf16x8 af[4], bfr[4];
    for (int i = 0; i < 4; ++i) {
      af[i]  = *(const bf16x8*)(&As[(wm + i * 16 + l16) * 32 + quad * 8]);
      bfr[i] = *(const bf16x8*)(&Bs[(wn + i * 16 + l16) * 32 + quad * 8]);
    }
    for (int i = 0; i < 4; ++i)
      for (int j = 0; j < 4; ++j)
        acc[i][j] = __builtin_amdgcn_mfma_f32_16x16x32_bf16(af[i], bfr[j], acc[i][j], 0, 0, 0);
  }

  int ncol = n0 + wn;  // this wave's 64-wide strip base = one full head
  if (ncol < 1280) {
    // Q (ncol<1024) or K: RoPE + RMS-norm*1.2
    __bf16* dstbase;
    if (ncol < 1024) dstbase = Qb + (size_t)(ncol >> 6) * 2048 * 64;          // head h
    else             dstbase = Kb + (size_t)((ncol - 1024) >> 6) * 2048 * 64; // head kvh
    int nheads = (ncol < 1024) ? 16 : 4;
    for (int i = 0; i < 4; ++i) {
      for (int r = 0; r < 4; ++r) {
        int m = m0 + wm + i * 16 + quad * 4 + r;
        int bb = m >> 11, t = m & 2047;
        float c0 = cosp[t * 32 + l16], c1 = cosp[t * 32 + 16 + l16];
        float s0 = sinp[t * 32 + l16], s1 = sinp[t * 32 + 16 + l16];
        float v0 = acc[i][0][r], v1 = acc[i][1][r], v2 = acc[i][2][r], v3 = acc[i][3][r];
        float r0 = v0 * c0 + v2 * s0;
        float r1 = v1 * c1 + v3 * s1;
        float r2 = v2 * c0 - v0 * s0;
        float r3 = v3 * c1 - v1 * s1;
        float ss = r0 * r0 + r1 * r1 + r2 * r2 + r3 * r3;
        ss += __shfl_xor(ss, 1, 64); ss += __shfl_xor(ss, 2, 64);
        ss += __shfl_xor(ss, 4, 64); ss += __shfl_xor(ss, 8, 64);
        float sc = rsqrtf(ss * (1.f / 64.f) + 1e-6f) * 1.2f;
        __bf16* dst = dstbase + ((size_t)bb * nheads * 2048 + t) * 64;
        dst[l16]      = (__bf16)(r0 * sc);
        dst[16 + l16] = (__bf16)(r1 * sc);
        dst[32 + l16] = (__bf16)(r2 * sc);
        dst[48 + l16] = (__bf16)(r3 * sc);
      }
    }
  } else {
    // V: v + gate*ve, store transposed Vt[(bb*4+kvh)*64 + d][t]
    int kvh = (ncol - 1280) >> 6;
    for (int i = 0; i < 4; ++i) {
      int mbase = m0 + wm + i * 16 + quad * 4;
      int bb = mbase >> 11;
      int t0 = mbase & 2047;
      float g4[4];
      for (int r = 0; r < 4; ++r) g4[r] = gate[(mbase + r) * 4 + kvh];
      for (int j = 0; j < 4; ++j) {
        int d = j * 16 + l16;
        bf16x4 pk;
        for (int r = 0; r < 4; ++r)
          pk[r] = (__bf16)(acc[i][j][r] + g4[r] * ve[(size_t)(mbase + r) * 256 + kvh * 64 + d]);
        *(bf16x4*)(Vt + ((size_t)(bb * 4 + kvh) * 64 + d) * 2048 + t0) = pk;
      }
    }
  }
}

// ---------------- 4) flash attention ----------------
// 512 thr / 8 waves, 128 q per block (16 per wave), 64-key tiles, pipelined K/V prefetch.
// Fixed-max softmax: ||q||,||k|| <= 9.64 -> |score| <= 11.62 < 12.
__global__ __launch_bounds__(512) void attn_kernel(
    const __bf16* __restrict__ Q, const __bf16* __restrict__ K,
    const __bf16* __restrict__ Vt, __bf16* __restrict__ Y,
    const int* __restrict__ winp) {
  const int T = 2048, D = 64, NH = 16, NKV = 4;
  int b = blockIdx.z, h = blockIdx.y;
  int qb = (15 - blockIdx.x) * 128;  // reversed: longest blocks dispatch first (LPT)
  int kvh = h >> 2;
  int tid = threadIdx.x, w = tid >> 6, lane = tid & 63, quad = lane >> 4, l16 = lane & 15;
  int window = *winp;
  int qw = qb + w * 16;

  __shared__ __bf16 Ks[64 * 72];
  __shared__ __bf16 Vs[64 * 72];
  __shared__ __bf16 Ps[8 * 16 * 72];

  const __bf16* Qbase = Q + ((size_t)(b * NH + h)) * T * D;
  bf16x8 qf0 = *(const bf16x8*)(Qbase + (size_t)(qw + l16) * D + quad * 8);
  bf16x8 qf1 = *(const bf16x8*)(Qbase + (size_t)(qw + l16) * D + quad * 8 + 32);

  const __bf16* Kbase = K  + ((size_t)(b * NKV + kvh)) * T * D;
  const __bf16* Vbase = Vt + ((size_t)(b * NKV + kvh)) * D * T;

  float lsum[4] = {0.f, 0.f, 0.f, 0.f};
  f32x4 zero = {0.f, 0.f, 0.f, 0.f};
  f32x4 o[4] = {zero, zero, zero, zero};

  int kstart = qb - window; if (kstart < 0) kstart = 0; kstart &= ~63;
  int kend = qb + 128;
  const float c1 = 0.125f * 1.44269504f;
  const float c2 = 12.0f * 1.44269504f;

  int sr = tid >> 3, sc8 = (tid & 7) * 8;  // stage: 512 thr x 8 elems = 64x64 tile
  bf16x8 kr = *(const bf16x8*)(Kbase + (size_t)(kstart + sr) * D + sc8);
  bf16x8 vr = *(const bf16x8*)(Vbase + (size_t)sr * T + kstart + sc8);

  for (int kt = kstart; kt < kend; kt += 64) {
    __syncthreads();
    *(bf16x8*)(&Ks[sr * 72 + sc8]) = kr;
    *(bf16x8*)(&Vs[sr * 72 + sc8]) = vr;
    __syncthreads();
    int ktn = kt + 64;
    if (ktn < kend) {  // prefetch next tile under this tile's compute
      kr = *(const bf16x8*)(Kbase + (size_t)(ktn + sr) * D + sc8);
      vr = *(const bf16x8*)(Vbase + (size_t)sr * T + ktn + sc8);
    }
    if (kt > qw + 15 || kt + 63 < qw - window) continue;

    f32x4 s[4];
    for (int kg = 0; kg < 4; ++kg) {
      bf16x8 k0 = *(const bf16x8*)(&Ks[(kg * 16 + l16) * 72 + quad * 8]);
      bf16x8 k1 = *(const bf16x8*)(&Ks[(kg * 16 + l16) * 72 + quad * 8 + 32]);
      s[kg] = __builtin_amdgcn_mfma_f32_16x16x32_bf16(qf0, k0, zero, 0, 0, 0);
      s[kg] = __builtin_amdgcn_mfma_f32_16x16x32_bf16(qf1, k1, s[kg], 0, 0, 0);
    }
    for (int r = 0; r < 4; ++r) {
      int q = qw + quad * 4 + r;
      for (int kg = 0; kg < 4; ++kg) {
        int ki = kt + kg * 16 + l16;
        bool ok = (ki <= q) && (q - ki <= window);
        float p = ok ? exp2f(s[kg][r] * c1 - c2) : 0.f;
        lsum[r] += p;
        Ps[w * 1152 + (quad * 4 + r) * 72 + kg * 16 + l16] = (__bf16)p;
      }
    }
    for (int koff = 0; koff < 64; koff += 32) {
      bf16x8 pf = *(const bf16x8*)(&Ps[w * 1152 + l16 * 72 + koff + quad * 8]);
      for (int j = 0; j < 4; ++j) {
        bf16x8 vf = *(const bf16x8*)(&Vs[(j * 16 + l16) * 72 + koff + quad * 8]);
        o[j] = __builtin_amdgcn_mfma_f32_16x16x32_bf16(pf, vf, o[j], 0, 0, 0);
      }
    }
  }

  for (int r = 0; r < 4; ++r) {
    float l = lsum[r];
    for (int off = 1; off < 16; off <<= 1) l += __shfl_xor(l, off, 64);
    float inv = 1.f / l;
    size_t base = ((size_t)(b * T + qw + quad * 4 + r)) * 1024 + h * 64 + l16;
    Y[base +  0] = (__bf16)(o[0][r] * inv);
    Y[base + 16] = (__bf16)(o[1][r] * inv);
    Y[base + 32] = (__bf16)(o[2][r] * inv);
    Y[base + 48] = (__bf16)(o[3][r] * inv);
  }
}

// ---------------- 5) proj GEMM (fp32 out) ----------------
__global__ __launch_bounds__(256) void gemm_bt(const __bf16* __restrict__ A,
                                               const __bf16* __restrict__ Bt,
                                               float* __restrict__ C,
                                               int M, int N, int K) {
  __shared__ __bf16 As[128 * 32];
  __shared__ __bf16 Bs[128 * 32];
  int tid = threadIdx.x;
  int m0 = blockIdx.y * 128, n0 = blockIdx.x * 128;
  int w = tid >> 6, lane = tid & 63, quad = lane >> 4, l16 = lane & 15;
  int wm = (w >> 1) * 64, wn = (w & 1) * 64;

  f32x4 zero = {0.f, 0.f, 0.f, 0.f};
  f32x4 acc[4][4];
  for (int i = 0; i < 4; ++i) for (int j = 0; j < 4; ++j) acc[i][j] = zero;

  int ch0 = w * 2, ch1 = w * 2 + 1;
  int rsub = lane >> 2, cc = (lane & 3) * 8;
  const __bf16* gA0 = A + (size_t)(m0 + ch0 * 16 + rsub) * K + cc;
  const __bf16* gA1 = A + (size_t)(m0 + ch1 * 16 + rsub) * K + cc;
  const __bf16* gB0 = Bt + (size_t)(n0 + ch0 * 16 + rsub) * K + cc;
  const __bf16* gB1 = Bt + (size_t)(n0 + ch1 * 16 + rsub) * K + cc;
  __bf16* lA0 = &As[ch0 * 512]; __bf16* lA1 = &As[ch1 * 512];
  __bf16* lB0 = &Bs[ch0 * 512]; __bf16* lB1 = &Bs[ch1 * 512];

  for (int k0 = 0; k0 < K; k0 += 32) {
    __syncthreads();
    g2l16(gA0 + k0, lA0);
    g2l16(gA1 + k0, lA1);
    g2l16(gB0 + k0, lB0);
    g2l16(gB1 + k0, lB1);
    __syncthreads();
    bf16x8 af[4], bfr[4];
    for (int i = 0; i < 4; ++i) {
      af[i]  = *(const bf16x8*)(&As[(wm + i * 16 + l16) * 32 + quad * 8]);
      bfr[i] = *(const bf16x8*)(&Bs[(wn + i * 16 + l16) * 32 + quad * 8]);
    }
    for (int i = 0; i < 4; ++i)
      for (int j = 0; j < 4; ++j)
        acc[i][j] = __builtin_amdgcn_mfma_f32_16x16x32_bf16(af[i], bfr[j], acc[i][j], 0, 0, 0);
  }
  for (int i = 0; i < 4; ++i)
    for (int j = 0; j < 4; ++j)
      for (int r = 0; r < 4; ++r)
        C[(size_t)(m0 + wm + i * 16 + quad * 4 + r) * N + n0 + wn + j * 16 + l16] = acc[i][j][r];
}

// ---------------- launch ----------------
extern "C" void kernel_launch(void* const* d_in, const int* in_sizes, int n_in,
                              void* d_out, int out_size, void* d_ws, size_t ws_size,
                              hipStream_t stream) {
  const float* x     = (const float*)d_in[0];
  const float* ve    = (const float*)d_in[1];
  const float* cosp  = (const float*)d_in[2];
  const float* sinp  = (const float*)d_in[3];
  const float* Wq    = (const float*)d_in[4];
  const float* Wk    = (const float*)d_in[5];
  const float* Wv    = (const float*)d_in[6];
  const float* Wproj = (const float*)d_in[7];
  const float* Wg    = (const float*)d_in[8];
  const int*   win   = (const int*)d_in[9];
  float* out = (float*)d_out;

  char* ws = (char*)d_ws;
  __bf16* xb   = (__bf16*)(ws);                //  8,388,608  [4096][1024]
  __bf16* Wt   = (__bf16*)(ws + 8388608);      //  3,145,728  [1536][1024]
  __bf16* Wpt  = (__bf16*)(ws + 11534336);     //  2,097,152  [1024][1024]
  float*  gate = (float*)(ws + 13631488);      //     65,536  [4096][4]
  __bf16* Qb   = (__bf16*)(ws + 13697024);     //  8,388,608  [2][16][2048][64]
  __bf16* Kb   = (__bf16*)(ws + 22085632);     //  2,097,152  [2][4][2048][64]
  __bf16* Vt   = (__bf16*)(ws + 24182784);     //  2,097,152  [2][4][64][2048]
  __bf16* Y    = (__bf16*)(ws + 26279936);     //  8,388,608  [4096][1024] -> ends 34,668,544

  convert_gate<<<2048, 256, 0, stream>>>(x, xb, gate, Wg);
  transpose_weights<<<dim3(32, 32, 4), 256, 0, stream>>>(Wq, Wk, Wv, Wproj, Wt, Wpt);
  gemm_qkv<<<dim3(12, 32), 256, 0, stream>>>(xb, Wt, cosp, sinp, gate, ve, Qb, Kb, Vt);
  attn_kernel<<<dim3(16, 16, 2), 512, 0, stream>>>(Qb, Kb, Vt, Y, win);
  gemm_bt<<<dim3(8, 32), 256, 0, stream>>>(Y, Wpt, out, 4096, 1024, 1024);
}